// Round 6
// baseline (1877.372 us; speedup 1.0000x reference)
//
#include <hip/hip_runtime.h>
#include <hip/hip_bf16.h>
#include <stdint.h>

typedef __bf16 bf16x8 __attribute__((ext_vector_type(8)));
typedef float  f32x16 __attribute__((ext_vector_type(16)));

#define NH      4096
#define MB      1024
#define M2      2048
#define DIN     784
#define KPAD    832      /* 13*64 */
#define N_IN    8192
#define NLAYERS 24
#define NOUT    10

// GEMM geometry: 256x128 block tile, BK=64, 512 threads = 8 waves (4M x 2N),
// 64x64 output per wave via 2x2 mfma_32x32x16 fragments.
// LDS: 3-slot ring, slot = A[256][64]+B[128][64] = 48 KB. Read-ahead pipeline.
#define ASLOT   (256 * 64)            /* elements */
#define BSLOT   (128 * 64)
#define SLOT    (ASLOT + BSLOT)       /* 24576 elements = 48 KB */

__device__ __forceinline__ unsigned short f2bf(float x) {
  union { float f; unsigned u; } v; v.f = x;
  unsigned r = v.u + 0x7FFFu + ((v.u >> 16) & 1u);   // RNE (finite inputs)
  return (unsigned short)(r >> 16);
}
__device__ __forceinline__ float bf2f(unsigned short u) {
  union { unsigned u; float f; } v; v.u = ((unsigned)u) << 16; return v.f;
}

__device__ __forceinline__ void async16(const void* g, void* l) {
  __builtin_amdgcn_global_load_lds(
      (const __attribute__((address_space(1))) void*)g,
      (__attribute__((address_space(3))) void*)l, 16, 0, 0);
}

// ---------- weight/input conversion ----------
__global__ void k_conv_wsp(const float* __restrict__ W, const float* __restrict__ o,
                           unsigned short* __restrict__ out) {
  size_t i = ((size_t)blockIdx.x * blockDim.x + threadIdx.x) * 4;
  if (i >= (size_t)NH * NH) return;
  float4 w = *reinterpret_cast<const float4*>(W + i);
  int k = (int)(i & (NH - 1));
  float4 ov = *reinterpret_cast<const float4*>(o + k);
  ushort4 r;
  r.x = f2bf(w.x * ov.x); r.y = f2bf(w.y * ov.y);
  r.z = f2bf(w.z * ov.z); r.w = f2bf(w.w * ov.w);
  *reinterpret_cast<ushort4*>(out + i) = r;
}

__global__ void k_conv_pad(const float* __restrict__ in, unsigned short* __restrict__ out,
                           int rows, int kin, int kout) {
  size_t i = (size_t)blockIdx.x * blockDim.x + threadIdx.x;
  if (i >= (size_t)rows * kout) return;
  int r = (int)(i / kout), c = (int)(i % kout);
  out[i] = (c < kin) ? f2bf(in[(size_t)r * kin + c]) : (unsigned short)0;
}

// ---------- pipelined GEMM core: 3-slot ring, vmcnt(6), read-ahead fragments ----------
__device__ __forceinline__ void gemm_core(
    const unsigned short* __restrict__ Ag, const unsigned short* __restrict__ Bg,
    int K, int bm, int bn, unsigned short* lds, f32x16 acc[2][2])
{
  const int t    = threadIdx.x;
  const int lane = t & 63;
  const int wave = t >> 6;
  const int wm   = wave >> 1;          // 0..3 -> 64-row band
  const int wn   = wave & 1;           // 0..1 -> 64-col band
  const int l31  = lane & 31;
  const int hi   = lane >> 5;          // k-half of fragment

  // ---- staging offsets: linear LDS dest, pre-swizzled global source ----
  const int srow = t >> 3;
  const int sb   = ((t & 7) * 16) ^ ((srow & 7) << 4);
  const unsigned aG0 = (unsigned)((bm + srow) * K + (sb >> 1));
  const unsigned bG0 = (unsigned)((bn + srow) * K + (sb >> 1));

  auto STAGE = [&](int slotIdx, int k0) {
    unsigned short* s = lds + slotIdx * SLOT;
#pragma unroll
    for (int j = 0; j < 4; ++j)
      async16(Ag + aG0 + (unsigned)(j * 64 * K + k0), s + t * 8 + j * 4096);
#pragma unroll
    for (int j = 0; j < 2; ++j)
      async16(Bg + bG0 + (unsigned)(j * 64 * K + k0), s + ASLOT + t * 8 + j * 4096);
  };

  // ---- fragment read offsets: A[row=l31][k=hi*8+j] per 32x32x16 operand rule ----
  // ks in 0..3 (16-k steps within BK=64); byte col = (ks*32 + hi*16) ^ swz(row)
  int aRd[4][2], bRd[4][2];
#pragma unroll
  for (int ks = 0; ks < 4; ++ks)
#pragma unroll
    for (int i = 0; i < 2; ++i) {
      const int ra = wm * 64 + i * 32 + l31;
      aRd[ks][i] = (ra * 128 + ((ks * 32 + hi * 16) ^ ((ra & 7) << 4))) >> 1;
      const int rb = wn * 64 + i * 32 + l31;
      bRd[ks][i] = (rb * 128 + ((ks * 32 + hi * 16) ^ ((rb & 7) << 4))) >> 1;
    }

  bf16x8 aX[2][2], bX[2][2], aY[2][2], bY[2][2];   // [ks2][frag]

  auto READS = [&](int slotIdx, int half, bf16x8 A4[2][2], bf16x8 B4[2][2]) {
    const unsigned short* base = lds + slotIdx * SLOT;
#pragma unroll
    for (int k2 = 0; k2 < 2; ++k2)
#pragma unroll
      for (int i = 0; i < 2; ++i) {
        A4[k2][i] = *reinterpret_cast<const bf16x8*>(base + aRd[half * 2 + k2][i]);
        B4[k2][i] = *reinterpret_cast<const bf16x8*>(base + ASLOT + bRd[half * 2 + k2][i]);
      }
  };
  auto MM = [&](const bf16x8 A4[2][2], const bf16x8 B4[2][2]) {
    __builtin_amdgcn_s_setprio(1);
#pragma unroll
    for (int k2 = 0; k2 < 2; ++k2)
#pragma unroll
      for (int mi = 0; mi < 2; ++mi)
#pragma unroll
        for (int ni = 0; ni < 2; ++ni)
          acc[mi][ni] = __builtin_amdgcn_mfma_f32_32x32x16_bf16(A4[k2][mi], B4[k2][ni], acc[mi][ni], 0, 0, 0);
    __builtin_amdgcn_s_setprio(0);
  };

  const int nt = K >> 6;
  // prologue: 2 K-tiles in flight; slot0 ready; read half 0 of tile 0 ahead
  STAGE(0, 0);
  STAGE(1, 64);
  asm volatile("s_waitcnt vmcnt(6)" ::: "memory");
  __builtin_amdgcn_s_barrier();
  __builtin_amdgcn_sched_barrier(0);
  READS(0, 0, aX, bX);

  int s0 = 0, s1 = 1, s2 = 2;
  for (int kt = 0; kt < nt; ++kt) {
    if (kt + 2 < nt) STAGE(s2, (kt + 2) << 6);   // slot s2: reads drained pre-prev-barrier
    READS(s0, 1, aY, bY);                        // half 1 of current tile
    MM(aX, bX);                                  // half 0 (read one phase ago)
    __builtin_amdgcn_sched_barrier(0);
    asm volatile("s_waitcnt lgkmcnt(0)" ::: "memory");   // drain my ds_reads (write-safety)
    __builtin_amdgcn_sched_barrier(0);
    if (kt + 1 < nt) {
      if (kt + 2 < nt) asm volatile("s_waitcnt vmcnt(6)" ::: "memory");  // retire STAGE(kt+1)
      else             asm volatile("s_waitcnt vmcnt(0)" ::: "memory");
      __builtin_amdgcn_s_barrier();              // slot kt+1 globally ready
      __builtin_amdgcn_sched_barrier(0);
      READS(s1, 0, aX, bX);                      // half 0 of next tile (read-ahead)
    }
    MM(aY, bY);                                  // half 1 (covers the reads above)
    const int n0 = s1, n1 = s2, n2 = s0;
    s0 = n0; s1 = n1; s2 = n2;
  }
}

// ---------- recurrent layer GEMM: Y = A @ Wsp'.T + b ; preact + relu->bf16 ----------
__global__ __launch_bounds__(512, 2) void k_gemm_layer(
    const unsigned short* __restrict__ A, const unsigned short* __restrict__ W,
    const float* __restrict__ bias, float* __restrict__ preact,
    unsigned short* __restrict__ Anext)
{
  __shared__ __align__(16) unsigned short lds[3 * SLOT];   // 144 KB
  const int bid = blockIdx.x;                      // 256 blocks
  const int s   = ((bid & 7) << 5) + (bid >> 3);   // XCD-aware bijective swizzle
  const int bm = (s >> 5) * 256;                   // 8 m-blocks
  const int bn = (s & 31) * 128;                   // 32 n-blocks
  f32x16 acc[2][2] = {};
  gemm_core(A, W, NH, bm, bn, lds, acc);

  const int lane = threadIdx.x & 63;
  const int wave = threadIdx.x >> 6;
  const int wmo = (wave >> 1) * 64, wno = (wave & 1) * 64;
  const int l31 = lane & 31, hi = lane >> 5;
#pragma unroll
  for (int mi = 0; mi < 2; ++mi) {
#pragma unroll
    for (int ni = 0; ni < 2; ++ni) {
      const int gn = bn + wno + ni * 32 + l31;     // C/D: col=lane&31
      const float bv = bias[gn];
#pragma unroll
      for (int r = 0; r < 16; ++r) {
        const int gm = bm + wmo + mi * 32 + (r & 3) + 8 * (r >> 2) + 4 * hi;
        const float y = acc[mi][ni][r] + bv;
        if (gm < MB) preact[(size_t)gm * NH + gn] = y;
        Anext[(size_t)gm * NH + gn] = f2bf(y > 0.f ? y : 0.f);
      }
    }
  }
}

// ---------- input GEMM: r = x @ W_in.T + b_in ; split a/b, preact0, relu ----------
__global__ __launch_bounds__(512, 2) void k_gemm_in(
    const unsigned short* __restrict__ X, const unsigned short* __restrict__ W,
    const float* __restrict__ bias, float* __restrict__ preact0,
    unsigned short* __restrict__ A0)
{
  __shared__ __align__(16) unsigned short lds[3 * SLOT];
  const int bid = blockIdx.x;                      // 256 blocks
  const int s   = ((bid & 7) << 5) + (bid >> 3);
  const int bm = (s >> 6) * 256;                   // 4 m-blocks
  const int bn = (s & 63) * 128;                   // 64 n-blocks
  f32x16 acc[2][2] = {};
  gemm_core(X, W, KPAD, bm, bn, lds, acc);

  const int lane = threadIdx.x & 63;
  const int wave = threadIdx.x >> 6;
  const int wmo = (wave >> 1) * 64, wno = (wave & 1) * 64;
  const int l31 = lane & 31, hi = lane >> 5;
#pragma unroll
  for (int mi = 0; mi < 2; ++mi) {
#pragma unroll
    for (int ni = 0; ni < 2; ++ni) {
      const int gn = bn + wno + ni * 32 + l31;
      const float bv = bias[gn];
#pragma unroll
      for (int r = 0; r < 16; ++r) {
        const int gm = bm + wmo + mi * 32 + (r & 3) + 8 * (r >> 2) + 4 * hi;
        const float y = acc[mi][ni][r] + bv;
        const unsigned short rl = f2bf(y > 0.f ? y : 0.f);
        if (gn < NH) {                       // "a" stream
          preact0[(size_t)gm * NH + gn] = y;
          A0[(size_t)gm * NH + gn] = rl;
        } else {                             // "b" stream -> rows 1024..2047
          A0[(size_t)(MB + gm) * NH + (gn - NH)] = rl;
        }
      }
    }
  }
}

// ---------- final head: out = (A * of) @ W_f.T + b_f  (N=10) ----------
__global__ void k_final(const unsigned short* __restrict__ A,
                        const float* __restrict__ Wf, const float* __restrict__ of,
                        const float* __restrict__ bf_, float* __restrict__ out)
{
  const int m = blockIdx.x;        // 0..2047
  const int t = threadIdx.x;       // 256
  float accj[NOUT] = {};
  for (int k = t; k < NH; k += 256) {
    const float a = bf2f(A[(size_t)m * NH + k]) * of[k];
#pragma unroll
    for (int j = 0; j < NOUT; ++j) accj[j] += a * Wf[j * NH + k];
  }
  __shared__ float red[4][NOUT];
#pragma unroll
  for (int j = 0; j < NOUT; ++j) {
    float v = accj[j];
    for (int off = 32; off > 0; off >>= 1) v += __shfl_down(v, off);
    if ((t & 63) == 0) red[t >> 6][j] = v;
  }
  __syncthreads();
  if (t < NOUT) {
    const float s = red[0][t] + red[1][t] + red[2][t] + red[3][t] + bf_[t];
    out[(size_t)m * NOUT + t] = s;
  }
}

extern "C" void kernel_launch(void* const* d_in, const int* in_sizes, int n_in,
                              void* d_out, int out_size, void* d_ws, size_t ws_size,
                              hipStream_t stream) {
  const float* x     = (const float*)d_in[0];
  const float* W_in  = (const float*)d_in[1];
  const float* b_in  = (const float*)d_in[2];
  const float* keysp = (const float*)d_in[3];
  const float* W_sp  = (const float*)d_in[4];
  const float* b_sp  = (const float*)d_in[5];
  const float* keyf  = (const float*)d_in[6];
  const float* W_f   = (const float*)d_in[7];
  const float* b_f   = (const float*)d_in[8];

  float* out    = (float*)d_out;
  float* preact = out + (size_t)2 * MB * NOUT;  // 25 x 1024 x 4096

  char* ws = (char*)d_ws;
  unsigned short* Wsp_bf = (unsigned short*)ws;  ws += (size_t)NH * NH * 2;
  unsigned short* A0     = (unsigned short*)ws;  ws += (size_t)M2 * NH * 2;
  unsigned short* A1     = (unsigned short*)ws;  ws += (size_t)M2 * NH * 2;
  unsigned short* Win_bf = (unsigned short*)ws;  ws += (size_t)N_IN * KPAD * 2;
  unsigned short* X_bf   = (unsigned short*)ws;  ws += (size_t)MB * KPAD * 2;

  k_conv_wsp<<<(NH * (size_t)NH / 4 + 255) / 256, 256, 0, stream>>>(W_sp, keysp, Wsp_bf);
  k_conv_pad<<<((size_t)N_IN * KPAD + 255) / 256, 256, 0, stream>>>(W_in, Win_bf, N_IN, DIN, KPAD);
  k_conv_pad<<<((size_t)MB * KPAD + 255) / 256, 256, 0, stream>>>(x, X_bf, MB, DIN, KPAD);

  // input GEMM: M=1024, N=8192, K=832 -> 4*64 = 256 blocks
  k_gemm_in<<<256, 512, 0, stream>>>(X_bf, Win_bf, b_in, preact, A0);

  // 24 recurrent layers: M=2048, N=4096, K=4096 -> 8*32 = 256 blocks
  unsigned short* Ain = A0;
  unsigned short* Aout = A1;
  for (int tlay = 0; tlay < NLAYERS; ++tlay) {
    float* pre = preact + (size_t)(tlay + 1) * MB * NH;
    k_gemm_layer<<<256, 512, 0, stream>>>(Ain, Wsp_bf, b_sp, pre, Aout);
    unsigned short* tmp = Ain; Ain = Aout; Aout = tmp;
  }

  k_final<<<M2, 256, 0, stream>>>(Ain, W_f, keyf, b_f, out);
}

// Round 7
// 1738.943 us; speedup vs baseline: 1.0796x; 1.0796x over previous
//
#include <hip/hip_runtime.h>
#include <hip/hip_bf16.h>
#include <stdint.h>

typedef __bf16 bf16x8 __attribute__((ext_vector_type(8)));
typedef float  f32x4  __attribute__((ext_vector_type(4)));

#define NH      4096
#define MB      1024
#define M2      2048
#define DIN     784
#define KPAD    832      /* 13*64 */
#define N_IN    8192
#define NLAYERS 24
#define NOUT    10

// GEMM geometry: 256x128 block tile, BK=64, 512 threads = 8 waves (4M x 2N),
// 64x64 per wave, 16x16x32 MFMA. LDS: 3-slot ring, slot = A[256][64]+B[128][64].
// Schedule: m201-style phase lockstep — per K-tile 2 phases, each
// {8 ds_read + 3 stage -> barrier -> lgkm(0) -> setprio+16 MFMA -> barrier},
// counted vmcnt(6) once per tile.
#define ASLOT   (256 * 64)            /* elements */
#define BSLOT   (128 * 64)
#define SLOT    (ASLOT + BSLOT)       /* 24576 elements = 48 KB */

__device__ __forceinline__ unsigned short f2bf(float x) {
  union { float f; unsigned u; } v; v.f = x;
  unsigned r = v.u + 0x7FFFu + ((v.u >> 16) & 1u);   // RNE (finite inputs)
  return (unsigned short)(r >> 16);
}
__device__ __forceinline__ float bf2f(unsigned short u) {
  union { unsigned u; float f; } v; v.u = ((unsigned)u) << 16; return v.f;
}

__device__ __forceinline__ void async16(const void* g, void* l) {
  __builtin_amdgcn_global_load_lds(
      (const __attribute__((address_space(1))) void*)g,
      (__attribute__((address_space(3))) void*)l, 16, 0, 0);
}

// ---------- weight/input conversion ----------
__global__ void k_conv_wsp(const float* __restrict__ W, const float* __restrict__ o,
                           unsigned short* __restrict__ out) {
  size_t i = ((size_t)blockIdx.x * blockDim.x + threadIdx.x) * 4;
  if (i >= (size_t)NH * NH) return;
  float4 w = *reinterpret_cast<const float4*>(W + i);
  int k = (int)(i & (NH - 1));
  float4 ov = *reinterpret_cast<const float4*>(o + k);
  ushort4 r;
  r.x = f2bf(w.x * ov.x); r.y = f2bf(w.y * ov.y);
  r.z = f2bf(w.z * ov.z); r.w = f2bf(w.w * ov.w);
  *reinterpret_cast<ushort4*>(out + i) = r;
}

__global__ void k_conv_pad(const float* __restrict__ in, unsigned short* __restrict__ out,
                           int rows, int kin, int kout) {
  size_t i = (size_t)blockIdx.x * blockDim.x + threadIdx.x;
  if (i >= (size_t)rows * kout) return;
  int r = (int)(i / kout), c = (int)(i % kout);
  out[i] = (c < kin) ? f2bf(in[(size_t)r * kin + c]) : (unsigned short)0;
}

// ---------- phase-lockstep GEMM core: 3-slot ring, vmcnt(6) once/tile ----------
__device__ __forceinline__ void gemm_core(
    const unsigned short* __restrict__ Ag, const unsigned short* __restrict__ Bg,
    int K, int bm, int bn, unsigned short* lds, f32x4 acc[4][4])
{
  const int t    = threadIdx.x;
  const int lane = t & 63;
  const int wave = t >> 6;
  const int wm   = wave >> 1;          // 0..3 -> 64-row band
  const int wn   = wave & 1;           // 0..1 -> 64-col band
  const int l15  = lane & 15;
  const int lkb  = (lane >> 4) * 16;   // byte offset of k-group within row

  // ---- staging offsets: linear LDS dest, pre-swizzled global source ----
  const int srow = t >> 3;
  const int sb   = ((t & 7) * 16) ^ ((srow & 7) << 4);
  const unsigned aG0 = (unsigned)((bm + srow) * K + (sb >> 1));
  const unsigned bG0 = (unsigned)((bn + srow) * K + (sb >> 1));

  // half-tile stage: part 0 = A rows 0..127 + B rows 0..63; part 1 = rest.
  auto STAGE_P = [&](int slotIdx, int k0, int part) {
    unsigned short* s = lds + slotIdx * SLOT;
    const int ja = part * 2;
    async16(Ag + aG0 + (unsigned)((ja + 0) * 64 * K + k0), s + t * 8 + (ja + 0) * 4096);
    async16(Ag + aG0 + (unsigned)((ja + 1) * 64 * K + k0), s + t * 8 + (ja + 1) * 4096);
    async16(Bg + bG0 + (unsigned)(part * 64 * K + k0), s + ASLOT + t * 8 + part * 4096);
  };

  // ---- fragment read offsets (elements within slot), XOR-swizzled ----
  int aRd[2][4], bRd[2][4];
#pragma unroll
  for (int kk = 0; kk < 2; ++kk)
#pragma unroll
    for (int i = 0; i < 4; ++i) {
      const int ra = wm * 64 + i * 16 + l15;
      aRd[kk][i] = (ra * 128 + ((kk * 64 + lkb) ^ ((ra & 7) << 4))) >> 1;
      const int rb = wn * 64 + i * 16 + l15;
      bRd[kk][i] = (rb * 128 + ((kk * 64 + lkb) ^ ((rb & 7) << 4))) >> 1;
    }

  const int nt = K >> 6;
  // prologue: stage tiles 0 and 1 fully (12 loads); make tile 0 ready.
  STAGE_P(0, 0, 0);  STAGE_P(0, 0, 1);
  STAGE_P(1, 64, 0); STAGE_P(1, 64, 1);
  asm volatile("s_waitcnt vmcnt(6)" ::: "memory");   // retire tile 0's 6 loads
  __builtin_amdgcn_s_barrier();

  int s0 = 0, s2 = 2;
  for (int kt = 0; kt < nt; ++kt) {
    const unsigned short* base = lds + s0 * SLOT;
#pragma unroll
    for (int half = 0; half < 2; ++half) {
      // --- pre-barrier: ds_read this phase's fragments + stage part of kt+2 ---
      bf16x8 A4[4], B4[4];
#pragma unroll
      for (int i = 0; i < 4; ++i) A4[i] = *reinterpret_cast<const bf16x8*>(base + aRd[half][i]);
#pragma unroll
      for (int i = 0; i < 4; ++i) B4[i] = *reinterpret_cast<const bf16x8*>(base + ASLOT + bRd[half][i]);
      if (kt + 2 < nt) STAGE_P(s2, (kt + 2) << 6, half);
      if (half == 1) {                                 // once per K-tile
        if (kt + 2 < nt)      asm volatile("s_waitcnt vmcnt(6)" ::: "memory");
        else if (kt + 1 < nt) asm volatile("s_waitcnt vmcnt(0)" ::: "memory");
      }
      __builtin_amdgcn_s_barrier();
      asm volatile("s_waitcnt lgkmcnt(0)" ::: "memory");
      __builtin_amdgcn_sched_barrier(0);
      __builtin_amdgcn_s_setprio(1);
#pragma unroll
      for (int mi = 0; mi < 4; ++mi)
#pragma unroll
        for (int ni = 0; ni < 4; ++ni)
          acc[mi][ni] = __builtin_amdgcn_mfma_f32_16x16x32_bf16(A4[mi], B4[ni], acc[mi][ni], 0, 0, 0);
      __builtin_amdgcn_s_setprio(0);
      __builtin_amdgcn_s_barrier();
    }
    const int ns0 = (s0 == 2) ? 0 : s0 + 1;
    const int ns2 = (s2 == 2) ? 0 : s2 + 1;
    s0 = ns0; s2 = ns2;
  }
}

// ---------- recurrent layer GEMM: Y = A @ Wsp'.T + b ; preact + relu->bf16 ----------
__global__ __launch_bounds__(512, 2) void k_gemm_layer(
    const unsigned short* __restrict__ A, const unsigned short* __restrict__ W,
    const float* __restrict__ bias, float* __restrict__ preact,
    unsigned short* __restrict__ Anext)
{
  __shared__ __align__(16) unsigned short lds[3 * SLOT];   // 144 KB
  const int bid = blockIdx.x;                      // 256 blocks
  const int s   = ((bid & 7) << 5) + (bid >> 3);   // XCD-aware bijective swizzle
  const int bm = (s >> 5) * 256;                   // 8 m-blocks
  const int bn = (s & 31) * 128;                   // 32 n-blocks
  f32x4 acc[4][4] = {};
  gemm_core(A, W, NH, bm, bn, lds, acc);

  const int lane = threadIdx.x & 63;
  const int wave = threadIdx.x >> 6;
  const int wm = (wave >> 1) * 64, wn = (wave & 1) * 64;
  const int l15 = lane & 15;
#pragma unroll
  for (int mi = 0; mi < 4; ++mi) {
    const int gm0 = bm + wm + mi * 16 + (lane >> 4) * 4;   // C/D: row=(lane>>4)*4+r
#pragma unroll
    for (int ni = 0; ni < 4; ++ni) {
      const int gn = bn + wn + ni * 16 + l15;              // C/D: col=lane&15
      const float bv = bias[gn];
#pragma unroll
      for (int r = 0; r < 4; ++r) {
        const int gm = gm0 + r;
        const float y = acc[mi][ni][r] + bv;
        if (gm < MB) preact[(size_t)gm * NH + gn] = y;
        Anext[(size_t)gm * NH + gn] = f2bf(y > 0.f ? y : 0.f);
      }
    }
  }
}

// ---------- input GEMM: r = x @ W_in.T + b_in ; split a/b, preact0, relu ----------
__global__ __launch_bounds__(512, 2) void k_gemm_in(
    const unsigned short* __restrict__ X, const unsigned short* __restrict__ W,
    const float* __restrict__ bias, float* __restrict__ preact0,
    unsigned short* __restrict__ A0)
{
  __shared__ __align__(16) unsigned short lds[3 * SLOT];
  const int bid = blockIdx.x;                      // 256 blocks
  const int s   = ((bid & 7) << 5) + (bid >> 3);
  const int bm = (s >> 6) * 256;                   // 4 m-blocks
  const int bn = (s & 63) * 128;                   // 64 n-blocks
  f32x4 acc[4][4] = {};
  gemm_core(X, W, KPAD, bm, bn, lds, acc);

  const int lane = threadIdx.x & 63;
  const int wave = threadIdx.x >> 6;
  const int wm = (wave >> 1) * 64, wn = (wave & 1) * 64;
  const int l15 = lane & 15;
#pragma unroll
  for (int mi = 0; mi < 4; ++mi) {
    const int gm0 = bm + wm + mi * 16 + (lane >> 4) * 4;
#pragma unroll
    for (int ni = 0; ni < 4; ++ni) {
      const int gn = bn + wn + ni * 16 + l15;
      const float bv = bias[gn];
#pragma unroll
      for (int r = 0; r < 4; ++r) {
        const int gm = gm0 + r;
        const float y = acc[mi][ni][r] + bv;
        const unsigned short rl = f2bf(y > 0.f ? y : 0.f);
        if (gn < NH) {                       // "a" stream
          preact0[(size_t)gm * NH + gn] = y;
          A0[(size_t)gm * NH + gn] = rl;
        } else {                             // "b" stream -> rows 1024..2047
          A0[(size_t)(MB + gm) * NH + (gn - NH)] = rl;
        }
      }
    }
  }
}

// ---------- final head: out = (A * of) @ W_f.T + b_f  (N=10) ----------
__global__ void k_final(const unsigned short* __restrict__ A,
                        const float* __restrict__ Wf, const float* __restrict__ of,
                        const float* __restrict__ bf_, float* __restrict__ out)
{
  const int m = blockIdx.x;        // 0..2047
  const int t = threadIdx.x;       // 256
  float accj[NOUT] = {};
  for (int k = t; k < NH; k += 256) {
    const float a = bf2f(A[(size_t)m * NH + k]) * of[k];
#pragma unroll
    for (int j = 0; j < NOUT; ++j) accj[j] += a * Wf[j * NH + k];
  }
  __shared__ float red[4][NOUT];
#pragma unroll
  for (int j = 0; j < NOUT; ++j) {
    float v = accj[j];
    for (int off = 32; off > 0; off >>= 1) v += __shfl_down(v, off);
    if ((t & 63) == 0) red[t >> 6][j] = v;
  }
  __syncthreads();
  if (t < NOUT) {
    const float s = red[0][t] + red[1][t] + red[2][t] + red[3][t] + bf_[t];
    out[(size_t)m * NOUT + t] = s;
  }
}

extern "C" void kernel_launch(void* const* d_in, const int* in_sizes, int n_in,
                              void* d_out, int out_size, void* d_ws, size_t ws_size,
                              hipStream_t stream) {
  const float* x     = (const float*)d_in[0];
  const float* W_in  = (const float*)d_in[1];
  const float* b_in  = (const float*)d_in[2];
  const float* keysp = (const float*)d_in[3];
  const float* W_sp  = (const float*)d_in[4];
  const float* b_sp  = (const float*)d_in[5];
  const float* keyf  = (const float*)d_in[6];
  const float* W_f   = (const float*)d_in[7];
  const float* b_f   = (const float*)d_in[8];

  float* out    = (float*)d_out;
  float* preact = out + (size_t)2 * MB * NOUT;  // 25 x 1024 x 4096

  char* ws = (char*)d_ws;
  unsigned short* Wsp_bf = (unsigned short*)ws;  ws += (size_t)NH * NH * 2;
  unsigned short* A0     = (unsigned short*)ws;  ws += (size_t)M2 * NH * 2;
  unsigned short* A1     = (unsigned short*)ws;  ws += (size_t)M2 * NH * 2;
  unsigned short* Win_bf = (unsigned short*)ws;  ws += (size_t)N_IN * KPAD * 2;
  unsigned short* X_bf   = (unsigned short*)ws;  ws += (size_t)MB * KPAD * 2;

  k_conv_wsp<<<(NH * (size_t)NH / 4 + 255) / 256, 256, 0, stream>>>(W_sp, keysp, Wsp_bf);
  k_conv_pad<<<((size_t)N_IN * KPAD + 255) / 256, 256, 0, stream>>>(W_in, Win_bf, N_IN, DIN, KPAD);
  k_conv_pad<<<((size_t)MB * KPAD + 255) / 256, 256, 0, stream>>>(x, X_bf, MB, DIN, KPAD);

  // input GEMM: M=1024, N=8192, K=832 -> 4*64 = 256 blocks
  k_gemm_in<<<256, 512, 0, stream>>>(X_bf, Win_bf, b_in, preact, A0);

  // 24 recurrent layers: M=2048, N=4096, K=4096 -> 8*32 = 256 blocks
  unsigned short* Ain = A0;
  unsigned short* Aout = A1;
  for (int tlay = 0; tlay < NLAYERS; ++tlay) {
    float* pre = preact + (size_t)(tlay + 1) * MB * NH;
    k_gemm_layer<<<256, 512, 0, stream>>>(Ain, Wsp_bf, b_sp, pre, Aout);
    unsigned short* tmp = Ain; Ain = Aout; Aout = tmp;
  }

  k_final<<<M2, 256, 0, stream>>>(Ain, W_f, keyf, b_f, out);
}

// Round 8
// 1637.152 us; speedup vs baseline: 1.1467x; 1.0622x over previous
//
#include <hip/hip_runtime.h>
#include <hip/hip_bf16.h>
#include <stdint.h>

typedef __bf16 bf16x8 __attribute__((ext_vector_type(8)));
typedef float  f32x4  __attribute__((ext_vector_type(4)));

#define NH      4096
#define MB      1024
#define M2      2048
#define DIN     784
#define KPAD    832      /* 13*64 */
#define N_IN    8192
#define NLAYERS 24
#define NOUT    10

// GEMM geometry: 256x128 block tile, BK=64, 512 threads = 8 waves.
// Producer-consumer: waves 0..3 = consumers (one per SIMD, 128x64 quadrant each,
// MFMA only); waves 4..7 = producers (global_load_lds staging only, own vmcnt).
// LDS: 3-slot ring, slot = A[256][64]+B[128][64] = 48 KB, total 144 KB.
#define ASLOT   (256 * 64)            /* elements */
#define BSLOT   (128 * 64)
#define SLOT    (ASLOT + BSLOT)       /* 24576 elements = 48 KB */

__device__ __forceinline__ unsigned short f2bf(float x) {
  union { float f; unsigned u; } v; v.f = x;
  unsigned r = v.u + 0x7FFFu + ((v.u >> 16) & 1u);   // RNE (finite inputs)
  return (unsigned short)(r >> 16);
}
__device__ __forceinline__ float bf2f(unsigned short u) {
  union { unsigned u; float f; } v; v.u = ((unsigned)u) << 16; return v.f;
}

__device__ __forceinline__ void async16(const void* g, void* l) {
  __builtin_amdgcn_global_load_lds(
      (const __attribute__((address_space(1))) void*)g,
      (__attribute__((address_space(3))) void*)l, 16, 0, 0);
}

// ---------- weight/input conversion ----------
__global__ void k_conv_wsp(const float* __restrict__ W, const float* __restrict__ o,
                           unsigned short* __restrict__ out) {
  size_t i = ((size_t)blockIdx.x * blockDim.x + threadIdx.x) * 4;
  if (i >= (size_t)NH * NH) return;
  float4 w = *reinterpret_cast<const float4*>(W + i);
  int k = (int)(i & (NH - 1));
  float4 ov = *reinterpret_cast<const float4*>(o + k);
  ushort4 r;
  r.x = f2bf(w.x * ov.x); r.y = f2bf(w.y * ov.y);
  r.z = f2bf(w.z * ov.z); r.w = f2bf(w.w * ov.w);
  *reinterpret_cast<ushort4*>(out + i) = r;
}

__global__ void k_conv_pad(const float* __restrict__ in, unsigned short* __restrict__ out,
                           int rows, int kin, int kout) {
  size_t i = (size_t)blockIdx.x * blockDim.x + threadIdx.x;
  if (i >= (size_t)rows * kout) return;
  int r = (int)(i / kout), c = (int)(i % kout);
  out[i] = (c < kin) ? f2bf(in[(size_t)r * kin + c]) : (unsigned short)0;
}

// ---------- producer-consumer GEMM core ----------
// Consumers (wave 0..3) return full 128x64 quadrant sums in acc[8][4].
__device__ __forceinline__ void gemm_core(
    const unsigned short* __restrict__ Ag, const unsigned short* __restrict__ Bg,
    int K, int bm, int bn, unsigned short* lds, f32x4 acc[8][4])
{
  const int t    = threadIdx.x;
  const int lane = t & 63;
  const int wave = t >> 6;
  const bool consumer = (wave < 4);
  const int nt = K >> 6;

  if (!consumer) {
    // ================= producer path (waves 4..7) =================
    const int pt     = t & 255;
    const int srow_p = pt >> 3;                     // 32 rows per wave-group
    const int sbp    = ((pt & 7) * 16) ^ ((srow_p & 7) << 4);
    const unsigned aGp = (unsigned)((bm + srow_p) * K + (sbp >> 1));
    const unsigned bGp = (unsigned)((bn + srow_p) * K + (sbp >> 1));

    auto STAGE = [&](int slotIdx, int k0) {          // 12 async16 per producer wave
      unsigned short* s = lds + slotIdx * SLOT;
#pragma unroll
      for (int j = 0; j < 8; ++j)
        async16(Ag + aGp + (unsigned)(j * 32 * K + k0), s + j * 2048 + pt * 8);
#pragma unroll
      for (int j = 0; j < 4; ++j)
        async16(Bg + bGp + (unsigned)(j * 32 * K + k0), s + ASLOT + j * 2048 + pt * 8);
    };

    STAGE(0, 0);
    if (nt > 1) { STAGE(1, 64); asm volatile("s_waitcnt vmcnt(12)" ::: "memory"); }
    else        {               asm volatile("s_waitcnt vmcnt(0)"  ::: "memory"); }
    __builtin_amdgcn_s_barrier();                    // tile 0 ready

    int s2 = 2;
    for (int kt = 0; kt < nt; ++kt) {
      if (kt + 2 < nt) {
        STAGE(s2, (kt + 2) << 6);
        asm volatile("s_waitcnt vmcnt(12)" ::: "memory");   // retire tile kt+1
      } else if (kt + 1 < nt) {
        asm volatile("s_waitcnt vmcnt(0)" ::: "memory");
      }
      __builtin_amdgcn_s_barrier();                  // tile kt+1 ready / slot freed
      s2 = (s2 == 2) ? 0 : s2 + 1;
    }
    return;                                          // producers done
  }

  // ================= consumer path (waves 0..3, one per SIMD) =================
  const int cm  = wave >> 1;           // 128-row band
  const int cn  = wave & 1;            // 64-col band
  const int l15 = lane & 15;
  const int lkb = (lane >> 4) * 16;    // byte offset of k-group within row

  int aRd[2][8], bRd[2][4];
#pragma unroll
  for (int kk = 0; kk < 2; ++kk) {
#pragma unroll
    for (int i = 0; i < 8; ++i) {
      const int ra = cm * 128 + i * 16 + l15;
      aRd[kk][i] = (ra * 128 + ((kk * 64 + lkb) ^ ((ra & 7) << 4))) >> 1;
    }
#pragma unroll
    for (int i = 0; i < 4; ++i) {
      const int rb = cn * 64 + i * 16 + l15;
      bRd[kk][i] = (rb * 128 + ((kk * 64 + lkb) ^ ((rb & 7) << 4))) >> 1;
    }
  }

  __builtin_amdgcn_s_barrier();                      // tile 0 ready
  int s0 = 0;
  for (int kt = 0; kt < nt; ++kt) {
    const unsigned short* base = lds + s0 * SLOT;
    __builtin_amdgcn_s_setprio(1);
#pragma unroll
    for (int kk = 0; kk < 2; ++kk) {
      bf16x8 a[8], b[4];
#pragma unroll
      for (int i = 0; i < 8; ++i) a[i] = *reinterpret_cast<const bf16x8*>(base + aRd[kk][i]);
#pragma unroll
      for (int i = 0; i < 4; ++i) b[i] = *reinterpret_cast<const bf16x8*>(base + ASLOT + bRd[kk][i]);
#pragma unroll
      for (int mi = 0; mi < 8; ++mi)
#pragma unroll
        for (int ni = 0; ni < 4; ++ni)
          acc[mi][ni] = __builtin_amdgcn_mfma_f32_16x16x32_bf16(a[mi], b[ni], acc[mi][ni], 0, 0, 0);
    }
    __builtin_amdgcn_s_setprio(0);
    asm volatile("s_waitcnt lgkmcnt(0)" ::: "memory");   // reads retired -> slot free
    __builtin_amdgcn_s_barrier();
    s0 = (s0 == 2) ? 0 : s0 + 1;
  }
}

// ---------- recurrent layer GEMM: Y = A @ Wsp'.T + b ; preact + relu->bf16 ----------
__global__ __launch_bounds__(512, 2) void k_gemm_layer(
    const unsigned short* __restrict__ A, const unsigned short* __restrict__ W,
    const float* __restrict__ bias, float* __restrict__ preact,
    unsigned short* __restrict__ Anext)
{
  __shared__ __align__(16) unsigned short lds[3 * SLOT];   // 144 KB
  const int bid = blockIdx.x;                      // 256 blocks
  const int s   = ((bid & 7) << 5) + (bid >> 3);   // XCD-aware bijective swizzle
  const int bm = (s >> 5) * 256;                   // 8 m-blocks
  const int bn = (s & 31) * 128;                   // 32 n-blocks
  f32x4 acc[8][4] = {};
  gemm_core(A, W, NH, bm, bn, lds, acc);

  const int wave = threadIdx.x >> 6;
  if (wave >= 4) return;                           // producers hold nothing
  const int lane = threadIdx.x & 63;
  const int cm = wave >> 1, cn = wave & 1;
  const int l15 = lane & 15;
#pragma unroll
  for (int mi = 0; mi < 8; ++mi) {
    const int gm0 = bm + cm * 128 + mi * 16 + (lane >> 4) * 4;   // C/D: row=(lane>>4)*4+r
#pragma unroll
    for (int ni = 0; ni < 4; ++ni) {
      const int gn = bn + cn * 64 + ni * 16 + l15;               // C/D: col=lane&15
      const float bv = bias[gn];
#pragma unroll
      for (int r = 0; r < 4; ++r) {
        const int gm = gm0 + r;
        const float y = acc[mi][ni][r] + bv;
        if (gm < MB) preact[(size_t)gm * NH + gn] = y;
        Anext[(size_t)gm * NH + gn] = f2bf(y > 0.f ? y : 0.f);
      }
    }
  }
}

// ---------- input GEMM: r = x @ W_in.T + b_in ; split a/b, preact0, relu ----------
__global__ __launch_bounds__(512, 2) void k_gemm_in(
    const unsigned short* __restrict__ X, const unsigned short* __restrict__ W,
    const float* __restrict__ bias, float* __restrict__ preact0,
    unsigned short* __restrict__ A0)
{
  __shared__ __align__(16) unsigned short lds[3 * SLOT];
  const int bid = blockIdx.x;                      // 256 blocks
  const int s   = ((bid & 7) << 5) + (bid >> 3);
  const int bm = (s >> 6) * 256;                   // 4 m-blocks
  const int bn = (s & 63) * 128;                   // 64 n-blocks
  f32x4 acc[8][4] = {};
  gemm_core(X, W, KPAD, bm, bn, lds, acc);

  const int wave = threadIdx.x >> 6;
  if (wave >= 4) return;
  const int lane = threadIdx.x & 63;
  const int cm = wave >> 1, cn = wave & 1;
  const int l15 = lane & 15;
#pragma unroll
  for (int mi = 0; mi < 8; ++mi) {
    const int gm0 = bm + cm * 128 + mi * 16 + (lane >> 4) * 4;
#pragma unroll
    for (int ni = 0; ni < 4; ++ni) {
      const int gn = bn + cn * 64 + ni * 16 + l15;
      const float bv = bias[gn];
#pragma unroll
      for (int r = 0; r < 4; ++r) {
        const int gm = gm0 + r;
        const float y = acc[mi][ni][r] + bv;
        const unsigned short rl = f2bf(y > 0.f ? y : 0.f);
        if (gn < NH) {                       // "a" stream
          preact0[(size_t)gm * NH + gn] = y;
          A0[(size_t)gm * NH + gn] = rl;
        } else {                             // "b" stream -> rows 1024..2047
          A0[(size_t)(MB + gm) * NH + (gn - NH)] = rl;
        }
      }
    }
  }
}

// ---------- final head: out = (A * of) @ W_f.T + b_f  (N=10) ----------
__global__ void k_final(const unsigned short* __restrict__ A,
                        const float* __restrict__ Wf, const float* __restrict__ of,
                        const float* __restrict__ bf_, float* __restrict__ out)
{
  const int m = blockIdx.x;        // 0..2047
  const int t = threadIdx.x;       // 256
  float accj[NOUT] = {};
  for (int k = t; k < NH; k += 256) {
    const float a = bf2f(A[(size_t)m * NH + k]) * of[k];
#pragma unroll
    for (int j = 0; j < NOUT; ++j) accj[j] += a * Wf[j * NH + k];
  }
  __shared__ float red[4][NOUT];
#pragma unroll
  for (int j = 0; j < NOUT; ++j) {
    float v = accj[j];
    for (int off = 32; off > 0; off >>= 1) v += __shfl_down(v, off);
    if ((t & 63) == 0) red[t >> 6][j] = v;
  }
  __syncthreads();
  if (t < NOUT) {
    const float s = red[0][t] + red[1][t] + red[2][t] + red[3][t] + bf_[t];
    out[(size_t)m * NOUT + t] = s;
  }
}

extern "C" void kernel_launch(void* const* d_in, const int* in_sizes, int n_in,
                              void* d_out, int out_size, void* d_ws, size_t ws_size,
                              hipStream_t stream) {
  const float* x     = (const float*)d_in[0];
  const float* W_in  = (const float*)d_in[1];
  const float* b_in  = (const float*)d_in[2];
  const float* keysp = (const float*)d_in[3];
  const float* W_sp  = (const float*)d_in[4];
  const float* b_sp  = (const float*)d_in[5];
  const float* keyf  = (const float*)d_in[6];
  const float* W_f   = (const float*)d_in[7];
  const float* b_f   = (const float*)d_in[8];

  float* out    = (float*)d_out;
  float* preact = out + (size_t)2 * MB * NOUT;  // 25 x 1024 x 4096

  char* ws = (char*)d_ws;
  unsigned short* Wsp_bf = (unsigned short*)ws;  ws += (size_t)NH * NH * 2;
  unsigned short* A0     = (unsigned short*)ws;  ws += (size_t)M2 * NH * 2;
  unsigned short* A1     = (unsigned short*)ws;  ws += (size_t)M2 * NH * 2;
  unsigned short* Win_bf = (unsigned short*)ws;  ws += (size_t)N_IN * KPAD * 2;
  unsigned short* X_bf   = (unsigned short*)ws;  ws += (size_t)MB * KPAD * 2;

  k_conv_wsp<<<(NH * (size_t)NH / 4 + 255) / 256, 256, 0, stream>>>(W_sp, keysp, Wsp_bf);
  k_conv_pad<<<((size_t)N_IN * KPAD + 255) / 256, 256, 0, stream>>>(W_in, Win_bf, N_IN, DIN, KPAD);
  k_conv_pad<<<((size_t)MB * KPAD + 255) / 256, 256, 0, stream>>>(x, X_bf, MB, DIN, KPAD);

  // input GEMM: M=1024, N=8192, K=832 -> 4*64 = 256 blocks
  k_gemm_in<<<256, 512, 0, stream>>>(X_bf, Win_bf, b_in, preact, A0);

  // 24 recurrent layers: M=2048, N=4096, K=4096 -> 8*32 = 256 blocks
  unsigned short* Ain = A0;
  unsigned short* Aout = A1;
  for (int tlay = 0; tlay < NLAYERS; ++tlay) {
    float* pre = preact + (size_t)(tlay + 1) * MB * NH;
    k_gemm_layer<<<256, 512, 0, stream>>>(Ain, Wsp_bf, b_sp, pre, Aout);
    unsigned short* tmp = Ain; Ain = Aout; Aout = tmp;
  }

  k_final<<<M2, 256, 0, stream>>>(Ain, W_f, keyf, b_f, out);
}

// Round 9
// 1610.170 us; speedup vs baseline: 1.1659x; 1.0168x over previous
//
#include <hip/hip_runtime.h>
#include <hip/hip_bf16.h>
#include <stdint.h>

typedef __bf16 bf16x8 __attribute__((ext_vector_type(8)));
typedef float  f32x4  __attribute__((ext_vector_type(4)));

#define NH      4096
#define MB      1024
#define M2      2048
#define DIN     784
#define KPAD    832      /* 13*64 */
#define N_IN    8192
#define NLAYERS 24
#define NOUT    10

// GEMM geometry: 128x128 block tile, BK=64, 256 threads = 4 waves (2M x 2N),
// 64x64 per wave, 16x16x32 MFMA. LDS: 2-slot double buffer,
// slot = A[128][64] + B[128][64] bf16 = 32 KB -> 64 KB total -> 2 blocks/CU.
// Loop: {STAGE(next); reads+MFMA(cur); vmcnt(0); barrier} — drain hidden by
// the co-resident block (m103/m114 wave-level overlap).
#define ASL     (128 * 64)            /* elements */
#define SLOT    (2 * ASL)             /* 16384 elements = 32 KB */

__device__ __forceinline__ unsigned short f2bf(float x) {
  union { float f; unsigned u; } v; v.f = x;
  unsigned r = v.u + 0x7FFFu + ((v.u >> 16) & 1u);   // RNE (finite inputs)
  return (unsigned short)(r >> 16);
}
__device__ __forceinline__ float bf2f(unsigned short u) {
  union { unsigned u; float f; } v; v.u = ((unsigned)u) << 16; return v.f;
}

__device__ __forceinline__ void async16(const void* g, void* l) {
  __builtin_amdgcn_global_load_lds(
      (const __attribute__((address_space(1))) void*)g,
      (__attribute__((address_space(3))) void*)l, 16, 0, 0);
}

// ---------- weight/input conversion ----------
__global__ void k_conv_wsp(const float* __restrict__ W, const float* __restrict__ o,
                           unsigned short* __restrict__ out) {
  size_t i = ((size_t)blockIdx.x * blockDim.x + threadIdx.x) * 4;
  if (i >= (size_t)NH * NH) return;
  float4 w = *reinterpret_cast<const float4*>(W + i);
  int k = (int)(i & (NH - 1));
  float4 ov = *reinterpret_cast<const float4*>(o + k);
  ushort4 r;
  r.x = f2bf(w.x * ov.x); r.y = f2bf(w.y * ov.y);
  r.z = f2bf(w.z * ov.z); r.w = f2bf(w.w * ov.w);
  *reinterpret_cast<ushort4*>(out + i) = r;
}

__global__ void k_conv_pad(const float* __restrict__ in, unsigned short* __restrict__ out,
                           int rows, int kin, int kout) {
  size_t i = (size_t)blockIdx.x * blockDim.x + threadIdx.x;
  if (i >= (size_t)rows * kout) return;
  int r = (int)(i / kout), c = (int)(i % kout);
  out[i] = (c < kin) ? f2bf(in[(size_t)r * kin + c]) : (unsigned short)0;
}

// ---------- 128x128 double-buffered GEMM core ----------
__device__ __forceinline__ void gemm_core(
    const unsigned short* __restrict__ Ag, const unsigned short* __restrict__ Bg,
    int K, int bm, int bn, unsigned short* lds, f32x4 acc[4][4])
{
  const int t    = threadIdx.x;
  const int lane = t & 63;
  const int wave = t >> 6;           // 0..3
  const int wm   = wave >> 1;        // 64-row band
  const int wn   = wave & 1;         // 64-col band
  const int l15  = lane & 15;
  const int lkb  = (lane >> 4) * 16; // byte offset of k-group within row

  // ---- staging offsets: linear LDS dest, pre-swizzled global source ----
  const int srow = t >> 3;                       // 0..31 (+j*32)
  const int sb   = ((t & 7) * 16) ^ ((srow & 7) << 4);
  const unsigned aG0 = (unsigned)((bm + srow) * K + (sb >> 1));
  const unsigned bG0 = (unsigned)((bn + srow) * K + (sb >> 1));

  auto STAGE = [&](int bufIdx, int k0) {         // 8 async16 per thread
    unsigned short* s = lds + bufIdx * SLOT;
#pragma unroll
    for (int j = 0; j < 4; ++j)
      async16(Ag + aG0 + (unsigned)(j * 32 * K + k0), s + t * 8 + j * 2048);
#pragma unroll
    for (int j = 0; j < 4; ++j)
      async16(Bg + bG0 + (unsigned)(j * 32 * K + k0), s + ASL + t * 8 + j * 2048);
  };

  // ---- fragment read offsets (elements within slot), XOR-swizzled ----
  int aRd[2][4], bRd[2][4];
#pragma unroll
  for (int kk = 0; kk < 2; ++kk)
#pragma unroll
    for (int i = 0; i < 4; ++i) {
      const int ra = wm * 64 + i * 16 + l15;
      aRd[kk][i] = (ra * 128 + ((kk * 64 + lkb) ^ ((ra & 7) << 4))) >> 1;
      const int rb = wn * 64 + i * 16 + l15;
      bRd[kk][i] = (rb * 128 + ((kk * 64 + lkb) ^ ((rb & 7) << 4))) >> 1;
    }

  const int nt = K >> 6;
  STAGE(0, 0);
  asm volatile("s_waitcnt vmcnt(0)" ::: "memory");
  __builtin_amdgcn_s_barrier();

  int buf = 0;
  for (int kt = 0; kt < nt; ++kt) {
    if (kt + 1 < nt) STAGE(buf ^ 1, (kt + 1) << 6);
    const unsigned short* base = lds + buf * SLOT;
    __builtin_amdgcn_s_setprio(1);
#pragma unroll
    for (int kk = 0; kk < 2; ++kk) {
      bf16x8 a[4], b[4];
#pragma unroll
      for (int i = 0; i < 4; ++i) a[i] = *reinterpret_cast<const bf16x8*>(base + aRd[kk][i]);
#pragma unroll
      for (int i = 0; i < 4; ++i) b[i] = *reinterpret_cast<const bf16x8*>(base + ASL + bRd[kk][i]);
#pragma unroll
      for (int mi = 0; mi < 4; ++mi)
#pragma unroll
        for (int ni = 0; ni < 4; ++ni)
          acc[mi][ni] = __builtin_amdgcn_mfma_f32_16x16x32_bf16(a[mi], b[ni], acc[mi][ni], 0, 0, 0);
    }
    __builtin_amdgcn_s_setprio(0);
    if (kt + 1 < nt) {
      asm volatile("s_waitcnt vmcnt(0)" ::: "memory");  // next buf fully written
      __builtin_amdgcn_s_barrier();                     // also: my reads of buf done
    }
    buf ^= 1;
  }
}

// ---------- recurrent layer GEMM: Y = A @ Wsp'.T + b ; preact + relu->bf16 ----------
__global__ __launch_bounds__(256, 2) void k_gemm_layer(
    const unsigned short* __restrict__ A, const unsigned short* __restrict__ W,
    const float* __restrict__ bias, float* __restrict__ preact,
    unsigned short* __restrict__ Anext)
{
  __shared__ __align__(16) unsigned short lds[2 * SLOT];   // 64 KB
  const int bid = blockIdx.x;            // 512 blocks = 16 bm x 32 bn
  const int xcd = bid & 7;
  const int idx = bid >> 3;              // 0..63
  const int bm  = (idx >> 2) * 128;      // 16 m-bands
  const int bn  = (xcd * 4 + (idx & 3)) * 128;   // XCD owns 4 bn-bands (W panel 4MB, L2-fit)
  f32x4 acc[4][4] = {};
  gemm_core(A, W, NH, bm, bn, lds, acc);

  const int lane = threadIdx.x & 63;
  const int wave = threadIdx.x >> 6;
  const int wm = (wave >> 1) * 64, wn = (wave & 1) * 64;
  const int l15 = lane & 15;
#pragma unroll
  for (int mi = 0; mi < 4; ++mi) {
    const int gm0 = bm + wm + mi * 16 + (lane >> 4) * 4;   // C/D: row=(lane>>4)*4+r
#pragma unroll
    for (int ni = 0; ni < 4; ++ni) {
      const int gn = bn + wn + ni * 16 + l15;              // C/D: col=lane&15
      const float bv = bias[gn];
#pragma unroll
      for (int r = 0; r < 4; ++r) {
        const int gm = gm0 + r;
        const float y = acc[mi][ni][r] + bv;
        if (gm < MB) preact[(size_t)gm * NH + gn] = y;
        Anext[(size_t)gm * NH + gn] = f2bf(y > 0.f ? y : 0.f);
      }
    }
  }
}

// ---------- input GEMM: r = x @ W_in.T + b_in ; split a/b, preact0, relu ----------
__global__ __launch_bounds__(256, 2) void k_gemm_in(
    const unsigned short* __restrict__ X, const unsigned short* __restrict__ W,
    const float* __restrict__ bias, float* __restrict__ preact0,
    unsigned short* __restrict__ A0)
{
  __shared__ __align__(16) unsigned short lds[2 * SLOT];
  const int bid = blockIdx.x;            // 512 blocks = 8 bm x 64 bn
  const int xcd = bid & 7;
  const int idx = bid >> 3;              // 0..63
  const int bm  = (idx >> 3) * 128;      // 8 m-bands
  const int bn  = (xcd * 8 + (idx & 7)) * 128;   // XCD owns 8 bn-bands (W_in panel ~1.7MB)
  f32x4 acc[4][4] = {};
  gemm_core(X, W, KPAD, bm, bn, lds, acc);

  const int lane = threadIdx.x & 63;
  const int wave = threadIdx.x >> 6;
  const int wm = (wave >> 1) * 64, wn = (wave & 1) * 64;
  const int l15 = lane & 15;
#pragma unroll
  for (int mi = 0; mi < 4; ++mi) {
    const int gm0 = bm + wm + mi * 16 + (lane >> 4) * 4;
#pragma unroll
    for (int ni = 0; ni < 4; ++ni) {
      const int gn = bn + wn + ni * 16 + l15;
      const float bv = bias[gn];
#pragma unroll
      for (int r = 0; r < 4; ++r) {
        const int gm = gm0 + r;
        const float y = acc[mi][ni][r] + bv;
        const unsigned short rl = f2bf(y > 0.f ? y : 0.f);
        if (gn < NH) {                       // "a" stream
          preact0[(size_t)gm * NH + gn] = y;
          A0[(size_t)gm * NH + gn] = rl;
        } else {                             // "b" stream -> rows 1024..2047
          A0[(size_t)(MB + gm) * NH + (gn - NH)] = rl;
        }
      }
    }
  }
}

// ---------- final head: out = (A * of) @ W_f.T + b_f  (N=10) ----------
__global__ void k_final(const unsigned short* __restrict__ A,
                        const float* __restrict__ Wf, const float* __restrict__ of,
                        const float* __restrict__ bf_, float* __restrict__ out)
{
  const int m = blockIdx.x;        // 0..2047
  const int t = threadIdx.x;       // 256
  float accj[NOUT] = {};
  for (int k = t; k < NH; k += 256) {
    const float a = bf2f(A[(size_t)m * NH + k]) * of[k];
#pragma unroll
    for (int j = 0; j < NOUT; ++j) accj[j] += a * Wf[j * NH + k];
  }
  __shared__ float red[4][NOUT];
#pragma unroll
  for (int j = 0; j < NOUT; ++j) {
    float v = accj[j];
    for (int off = 32; off > 0; off >>= 1) v += __shfl_down(v, off);
    if ((t & 63) == 0) red[t >> 6][j] = v;
  }
  __syncthreads();
  if (t < NOUT) {
    const float s = red[0][t] + red[1][t] + red[2][t] + red[3][t] + bf_[t];
    out[(size_t)m * NOUT + t] = s;
  }
}

extern "C" void kernel_launch(void* const* d_in, const int* in_sizes, int n_in,
                              void* d_out, int out_size, void* d_ws, size_t ws_size,
                              hipStream_t stream) {
  const float* x     = (const float*)d_in[0];
  const float* W_in  = (const float*)d_in[1];
  const float* b_in  = (const float*)d_in[2];
  const float* keysp = (const float*)d_in[3];
  const float* W_sp  = (const float*)d_in[4];
  const float* b_sp  = (const float*)d_in[5];
  const float* keyf  = (const float*)d_in[6];
  const float* W_f   = (const float*)d_in[7];
  const float* b_f   = (const float*)d_in[8];

  float* out    = (float*)d_out;
  float* preact = out + (size_t)2 * MB * NOUT;  // 25 x 1024 x 4096

  char* ws = (char*)d_ws;
  unsigned short* Wsp_bf = (unsigned short*)ws;  ws += (size_t)NH * NH * 2;
  unsigned short* A0     = (unsigned short*)ws;  ws += (size_t)M2 * NH * 2;
  unsigned short* A1     = (unsigned short*)ws;  ws += (size_t)M2 * NH * 2;
  unsigned short* Win_bf = (unsigned short*)ws;  ws += (size_t)N_IN * KPAD * 2;
  unsigned short* X_bf   = (unsigned short*)ws;  ws += (size_t)MB * KPAD * 2;

  k_conv_wsp<<<(NH * (size_t)NH / 4 + 255) / 256, 256, 0, stream>>>(W_sp, keysp, Wsp_bf);
  k_conv_pad<<<((size_t)N_IN * KPAD + 255) / 256, 256, 0, stream>>>(W_in, Win_bf, N_IN, DIN, KPAD);
  k_conv_pad<<<((size_t)MB * KPAD + 255) / 256, 256, 0, stream>>>(x, X_bf, MB, DIN, KPAD);

  // input GEMM: M=1024, N=8192, K=832 -> 8*64 = 512 blocks
  k_gemm_in<<<512, 256, 0, stream>>>(X_bf, Win_bf, b_in, preact, A0);

  // 24 recurrent layers: M=2048, N=4096, K=4096 -> 16*32 = 512 blocks
  unsigned short* Ain = A0;
  unsigned short* Aout = A1;
  for (int tlay = 0; tlay < NLAYERS; ++tlay) {
    float* pre = preact + (size_t)(tlay + 1) * MB * NH;
    k_gemm_layer<<<512, 256, 0, stream>>>(Ain, Wsp_bf, b_sp, pre, Aout);
    unsigned short* tmp = Ain; Ain = Aout; Aout = tmp;
  }

  k_final<<<M2, 256, 0, stream>>>(Ain, W_f, keyf, b_f, out);
}